// Round 4
// baseline (2058.860 us; speedup 1.0000x reference)
//
#include <hip/hip_runtime.h>

using bf16x8 = __attribute__((ext_vector_type(8))) short;
using f32x4  = __attribute__((ext_vector_type(4))) float;
typedef unsigned short u16;
typedef unsigned int   u32;
typedef unsigned long long u64;

#define MAX_SPIN 2000000

// B=256,T=256,D=64,H=512,O=10. 80 WGs x 512 thr. role = wg>>4: 0=A(L0 recur),
// 1=C(L1 recur), 2=B0, 3=B1 (z1 = W_ih1*h0 + b, n-halves), 4=D (z0 = W_ih0*x + b).
// bt = wg&15 (16 batch rows each). Recurrences are CU-LOCAL (h planes in LDS,
// W_hh stationary: 12 k-slices in VGPR + 4 k-slices in LDS). Cross-WG traffic
// (h0 ring, z0/z1 rings, depth 4) via relaxed agent atomics; flags are
// single-writer monotonic stage counters, prefetched one stage early.
// flA = h0[0..flA-1] shipped AND z0 consumed; flB0/flB1 = z1 half ready AND h0
// consumed; flC = z1 consumed; flD = z0 ready.

__device__ __forceinline__ float bf2f(u16 u){ union{u32 i;float f;}v; v.i=((u32)u)<<16; return v.f; }
__device__ __forceinline__ u16 f2bf(float f){ union{float f;u32 i;}v; v.f=f; u32 x=v.i; return (u16)((x+0x7FFFu+((x>>16)&1u))>>16); }
__device__ __forceinline__ bf16x8 load8f(const float* p){
  float4 a=*(const float4*)p; float4 b=*(const float4*)(p+4);
  bf16x8 r; r[0]=(short)f2bf(a.x); r[1]=(short)f2bf(a.y); r[2]=(short)f2bf(a.z); r[3]=(short)f2bf(a.w);
  r[4]=(short)f2bf(b.x); r[5]=(short)f2bf(b.y); r[6]=(short)f2bf(b.z); r[7]=(short)f2bf(b.w); return r;
}
__device__ __forceinline__ int  ldf(int* p){ return __hip_atomic_load(p, __ATOMIC_RELAXED, __HIP_MEMORY_SCOPE_AGENT); }
__device__ __forceinline__ void stf(int* p, int v){ __hip_atomic_store(p, v, __ATOMIC_RELAXED, __HIP_MEMORY_SCOPE_AGENT); }
__device__ __forceinline__ u64  ld64c(const u32* p){ return __hip_atomic_load((const u64*)p, __ATOMIC_RELAXED, __HIP_MEMORY_SCOPE_AGENT); }
__device__ __forceinline__ u32  ld32c(const u32* p){ return __hip_atomic_load(p, __ATOMIC_RELAXED, __HIP_MEMORY_SCOPE_AGENT); }
__device__ __forceinline__ void st32c(u32* p, u32 v){ __hip_atomic_store(p, v, __ATOMIC_RELAXED, __HIP_MEMORY_SCOPE_AGENT); }
__device__ __forceinline__ int waitge(int* p, int tgt){
  int v = ldf(p); int it = 0;
  while (v < tgt && ++it < MAX_SPIN){ __builtin_amdgcn_s_sleep(1); v = ldf(p); }
  return v;
}

__global__ void init_kernel(u32* p){ p[(blockIdx.x<<9) + threadIdx.x] = 0u; }

// A-frag from h planes: row=lrow, k=ks*32+lk8.., byte = lrow*1024 + ((ks*64 + lk8*2) ^ sw)
#define HFRAG(base, ks) (*(const bf16x8*)((base) + (lrow<<10) + ((((ks)<<6)+(lk8<<1)) ^ sw)))

__global__ void __launch_bounds__(512, 2)
rnn_kernel(const float* __restrict__ x,
           const float* __restrict__ w_ih0, const float* __restrict__ w_hh0,
           const float* __restrict__ b_ih0, const float* __restrict__ b_hh0,
           const float* __restrict__ w_ih1, const float* __restrict__ w_hh1,
           const float* __restrict__ b_ih1, const float* __restrict__ b_hh1,
           const float* __restrict__ fc1_w, const float* __restrict__ fc1_b,
           const float* __restrict__ fc2_w, const float* __restrict__ fc2_b,
           float* __restrict__ out,
           u32* __restrict__ ring0, u32* __restrict__ ringz0, u32* __restrict__ ringz1,
           int* __restrict__ flags)
{
  const int tid  = threadIdx.x;
  const int wg   = blockIdx.x;
  const int lane = tid & 63;
  const int ww   = tid >> 6;          // 0..7
  const int role = wg >> 4;           // 0..4
  const int bt   = wg & 15;
  const int b0   = bt << 4;
  const int lrow = lane & 15;
  const int lk8  = (lane >> 4) << 3;
  const int sw   = (lrow & 7) << 4;
  const int rb   = (lane >> 4) << 2;  // D-frag row base

  extern __shared__ char dummy_unused[];
  __shared__ char sm[163840];
  char* smWb  = sm;                    // 4 k-slices of W: [slice][n=512][32k] bf16, 128 KB
  char* smHhi = sm + 131072;           // h hi plane [16][512] bf16, 16 KB
  char* smHlo = sm + 147456;           // h lo plane, 16 KB

  int* flA  = flags + ((bt<<3) + 0)*16;
  int* flB0 = flags + ((bt<<3) + 1)*16;
  int* flB1 = flags + ((bt<<3) + 2)*16;
  int* flC  = flags + ((bt<<3) + 3)*16;
  int* flD  = flags + ((bt<<3) + 4)*16;

  if (role == 0 || role == 1) {
    // ================= recurrence WG (A: layer0, C: layer1) =================
    const float* Wp = (role == 0) ? w_hh0 : w_hh1;
    const int n0 = ww << 6;            // wave covers cols [n0, n0+64)
    bf16x8 wv[48];                     // [tile 0..3][ks 0..11]
#pragma unroll
    for (int tt = 0; tt < 4; ++tt) {
      int n = n0 + (tt<<4) + lrow;
#pragma unroll
      for (int ks = 0; ks < 12; ++ks)
        wv[tt*12+ks] = load8f(Wp + n*512 + (ks<<5) + lk8);
    }
#pragma unroll 1
    for (int it = 0; it < 16; ++it) {  // k-slices 12..15 -> LDS
      int cid = (it<<9) + tid;         // 0..8191
      int ss = cid >> 11, wc = cid & 2047;
      int n = wc >> 2, k0 = (wc & 3) << 3;
      bf16x8 v = load8f(Wp + n*512 + 384 + (ss<<5) + k0);
      *(bf16x8*)(smWb + (ss<<15) + (n<<6) + ((k0<<1) ^ ((n&3)<<4))) = v;
    }
    __syncthreads();

    const int wl0 = ((lane>>4)<<4) ^ ((lrow&3)<<4);  // W-LDS in-row offset
    int wlb[4];
#pragma unroll
    for (int tt = 0; tt < 4; ++tt) wlb[tt] = ((n0 + (tt<<4) + lrow)<<6) + wl0;

    float zpf[16];
    int f0v = 0, f1v = 0;
    u32* zring = (role == 0) ? ringz0 : ringz1;
    const u32* zbase = zring + bt*32768;
    if (role == 0) { f0v = waitge(flD, 1); }
    else           { f0v = waitge(flB0, 1); f1v = waitge(flB1, 1); }
#pragma unroll
    for (int tt = 0; tt < 4; ++tt) {
      int nc = n0 + (tt<<4) + lrow;
#pragma unroll
      for (int r = 0; r < 4; ++r)
        zpf[tt*4+r] = __uint_as_float(ld32c(zbase + ((rb+r)<<9) + nc));
    }

    for (int s = 0; s < 256; ++s) {
      f32x4 acc[4] = {{0,0,0,0},{0,0,0,0},{0,0,0,0},{0,0,0,0}};
      if (s > 0) {
#pragma unroll
        for (int ks = 0; ks < 16; ++ks) {
          bf16x8 ahi = HFRAG(smHhi, ks);
          bf16x8 alo = HFRAG(smHlo, ks);
          bf16x8 bw0, bw1, bw2, bw3;
          if (ks < 12) { bw0 = wv[ks]; bw1 = wv[12+ks]; bw2 = wv[24+ks]; bw3 = wv[36+ks]; }
          else {
            int sb = (ks-12) << 15;
            bw0 = *(const bf16x8*)(smWb + sb + wlb[0]);
            bw1 = *(const bf16x8*)(smWb + sb + wlb[1]);
            bw2 = *(const bf16x8*)(smWb + sb + wlb[2]);
            bw3 = *(const bf16x8*)(smWb + sb + wlb[3]);
          }
          acc[0] = __builtin_amdgcn_mfma_f32_16x16x32_bf16(ahi, bw0, acc[0], 0,0,0);
          acc[0] = __builtin_amdgcn_mfma_f32_16x16x32_bf16(alo, bw0, acc[0], 0,0,0);
          acc[1] = __builtin_amdgcn_mfma_f32_16x16x32_bf16(ahi, bw1, acc[1], 0,0,0);
          acc[1] = __builtin_amdgcn_mfma_f32_16x16x32_bf16(alo, bw1, acc[1], 0,0,0);
          acc[2] = __builtin_amdgcn_mfma_f32_16x16x32_bf16(ahi, bw2, acc[2], 0,0,0);
          acc[2] = __builtin_amdgcn_mfma_f32_16x16x32_bf16(alo, bw2, acc[2], 0,0,0);
          acc[3] = __builtin_amdgcn_mfma_f32_16x16x32_bf16(ahi, bw3, acc[3], 0,0,0);
          acc[3] = __builtin_amdgcn_mfma_f32_16x16x32_bf16(alo, bw3, acc[3], 0,0,0);
        }
      }
      u32 pk[16];
#pragma unroll
      for (int tt = 0; tt < 4; ++tt)
#pragma unroll
        for (int r = 0; r < 4; ++r) {
          float v = acc[tt][r] + zpf[tt*4+r];
          v = v > 0.f ? v : 0.f;
          u16 hi = f2bf(v); u16 lo = f2bf(v - bf2f(hi));
          pk[tt*4+r] = ((u32)hi << 16) | lo;
        }
      if (role == 0) {                 // ship h0[s] (off critical path)
        u32* rs = ring0 + bt*32768 + ((s&3)<<13);
#pragma unroll
        for (int tt = 0; tt < 4; ++tt) {
          int nc = n0 + (tt<<4) + lrow;
#pragma unroll
          for (int r = 0; r < 4; ++r) st32c(rs + ((rb+r)<<9) + nc, pk[tt*4+r]);
        }
      }
      __syncthreads();                 // all reads of h[s-1] done
#pragma unroll
      for (int tt = 0; tt < 4; ++tt) {
        int cc = n0 + (tt<<4) + lrow;
#pragma unroll
        for (int r = 0; r < 4; ++r) {
          int rr = rb + r;
          int o = (rr<<10) + (((cc<<1)) ^ ((rr&7)<<4));
          *(u16*)(smHhi + o) = (u16)(pk[tt*4+r] >> 16);
          *(u16*)(smHlo + o) = (u16)(pk[tt*4+r] & 0xFFFFu);
        }
      }
      if (role == 0) asm volatile("s_waitcnt vmcnt(0)" ::: "memory");
      __syncthreads();                 // h[s] planes visible; stores drained
      if (tid == 0) stf((role==0) ? flA : flC, s + 1);
      if (s < 255) {                   // prefetch z[s+1] + backpressure checks
        if (role == 0) {
          if (f0v < s+2) f0v = waitge(flD, s+2); else f0v = ldf(flD);
          int need = s - 2;            // ring0 slot reuse at s+1
          if (need > 0) {
            int bv0 = ldf(flB0), bv1 = ldf(flB1);
            if (bv0 < need) waitge(flB0, need);
            if (bv1 < need) waitge(flB1, need);
          }
        } else {
          if (f0v < s+2) f0v = waitge(flB0, s+2); else f0v = ldf(flB0);
          if (f1v < s+2) f1v = waitge(flB1, s+2); else f1v = ldf(flB1);
        }
        const u32* zs = zbase + (((s+1)&3)<<13);
#pragma unroll
        for (int tt = 0; tt < 4; ++tt) {
          int nc = n0 + (tt<<4) + lrow;
#pragma unroll
          for (int r = 0; r < 4; ++r)
            zpf[tt*4+r] = __uint_as_float(ld32c(zs + ((rb+r)<<9) + nc));
        }
      }
    }

    if (role == 1) {                   // ======== head: fc1(relu)+fc2 ========
      float* smF = (float*)sm;         // reuse W-LDS region
      if (tid < 128) {
        int r = tid >> 3, j = tid & 7;
        const float* wr = fc1_w + (j << 9);
        float accv = fc1_b[j];
        for (int k = 0; k < 512; ++k) {
          int o = (r<<10) + (((k<<1)) ^ ((r&7)<<4));
          float hv = bf2f(*(u16*)(smHhi + o)) + bf2f(*(u16*)(smHlo + o));
          accv += hv * wr[k];
        }
        smF[tid] = accv > 0.f ? accv : 0.f;
      }
      __syncthreads();
      if (tid < 160) {
        int bb = tid / 10, o = tid - bb*10;
        float accv = fc2_b[o];
        const float* w = fc2_w + (o << 3);
#pragma unroll
        for (int j = 0; j < 8; ++j) accv += smF[(bb<<3)+j] * w[j];
        out[(b0 + bb)*10 + o] = accv;
      }
    }
  } else if (role == 2 || role == 3) {
    // ================= B: z1 n-half = W_ih1 * h0[t] + b =================
    const int nb = (role - 2) << 8;
    const int n0 = nb + (ww << 5);     // wave covers 32 cols (2 tiles)
    bf16x8 wv[32];
    float bias[2];
#pragma unroll
    for (int tt = 0; tt < 2; ++tt) {
      int n = n0 + (tt<<4) + lrow;
#pragma unroll
      for (int ks = 0; ks < 16; ++ks)
        wv[tt*16+ks] = load8f(w_ih1 + n*512 + (ks<<5) + lk8);
      bias[tt] = b_ih1[n] + b_hh1[n];
    }
    int* flB = (role == 2) ? flB0 : flB1;
    int flAv = waitge(flA, 1), flCv = 0;
    u64 pf[8];
    {
      const u32* rs = ring0 + bt*32768;
#pragma unroll
      for (int k = 0; k < 8; ++k) {
        int q = tid + (k<<9); int r = q >> 8, c = q & 255;
        pf[k] = ld64c(rs + (r<<9) + (c<<1));
      }
    }
    for (int t = 0; t < 256; ++t) {
#pragma unroll
      for (int k = 0; k < 8; ++k) {    // unpack h0[t] -> planes
        int q = tid + (k<<9); int r = q >> 8, c = q & 255;
        u32 e0 = (u32)pf[k], e1 = (u32)(pf[k] >> 32);
        int o = (r<<10) + ((c<<2) ^ ((r&7)<<4));
        *(u32*)(smHhi + o) = (e0 >> 16) | (e1 & 0xFFFF0000u);
        *(u32*)(smHlo + o) = (e0 & 0xFFFFu) | (e1 << 16);
      }
      __syncthreads();
      f32x4 acc[2] = {{0,0,0,0},{0,0,0,0}};
#pragma unroll
      for (int ks = 0; ks < 16; ++ks) {
        bf16x8 ahi = HFRAG(smHhi, ks);
        bf16x8 alo = HFRAG(smHlo, ks);
        acc[0] = __builtin_amdgcn_mfma_f32_16x16x32_bf16(ahi, wv[ks],    acc[0], 0,0,0);
        acc[0] = __builtin_amdgcn_mfma_f32_16x16x32_bf16(alo, wv[ks],    acc[0], 0,0,0);
        acc[1] = __builtin_amdgcn_mfma_f32_16x16x32_bf16(ahi, wv[16+ks], acc[1], 0,0,0);
        acc[1] = __builtin_amdgcn_mfma_f32_16x16x32_bf16(alo, wv[16+ks], acc[1], 0,0,0);
      }
      {
        u32* zs = ringz1 + bt*32768 + ((t&3)<<13);
#pragma unroll
        for (int tt = 0; tt < 2; ++tt) {
          int nc = n0 + (tt<<4) + lrow;
#pragma unroll
          for (int r = 0; r < 4; ++r)
            st32c(zs + ((rb+r)<<9) + nc, __float_as_uint(acc[tt][r] + bias[tt]));
        }
      }
      __syncthreads();                 // plane reads done (next unpack overwrites)
      asm volatile("s_waitcnt vmcnt(0)" ::: "memory");
      __syncthreads();
      if (tid == 0) stf(flB, t + 1);
      if (t < 255) {
        if (flAv < t+2) flAv = waitge(flA, t+2); else flAv = ldf(flA);
        int need = t - 2;              // z1 slot reuse at t+1
        if (need > 0 && flCv < need) flCv = waitge(flC, need);
        else flCv = ldf(flC);
        const u32* rs = ring0 + bt*32768 + (((t+1)&3)<<13);
#pragma unroll
        for (int k = 0; k < 8; ++k) {
          int q = tid + (k<<9); int r = q >> 8, c = q & 255;
          pf[k] = ld64c(rs + (r<<9) + (c<<1));
        }
      }
    }
  } else {
    // ================= D: z0 = W_ih0 * x_s + b (runs ahead) =================
    const int n0 = ww << 6;
    bf16x8 wx[8];                      // [tile][ks2]
    float bz[4];
#pragma unroll
    for (int tt = 0; tt < 4; ++tt) {
      int n = n0 + (tt<<4) + lrow;
      wx[tt*2+0] = load8f(w_ih0 + n*64 + lk8);
      wx[tt*2+1] = load8f(w_ih0 + n*64 + 32 + lk8);
      bz[tt] = b_ih0[n] + b_hh0[n];
    }
    int flAv = 0;
    for (int s = 0; s < 256; ++s) {
      if (s >= 4 && flAv < s-3) flAv = waitge(flA, s-3);
      bf16x8 xh0, xl0, xh1, xl1;
      const float* xp = x + ((size_t)(b0 + lrow)*256 + s)*64 + lk8;
#pragma unroll
      for (int j = 0; j < 8; ++j) {
        float f0 = xp[j], f1 = xp[32+j];
        u16 h0 = f2bf(f0); xh0[j] = (short)h0; xl0[j] = (short)f2bf(f0 - bf2f(h0));
        u16 h1 = f2bf(f1); xh1[j] = (short)h1; xl1[j] = (short)f2bf(f1 - bf2f(h1));
      }
      f32x4 acc[4] = {{0,0,0,0},{0,0,0,0},{0,0,0,0},{0,0,0,0}};
#pragma unroll
      for (int tt = 0; tt < 4; ++tt) {
        acc[tt] = __builtin_amdgcn_mfma_f32_16x16x32_bf16(xh0, wx[tt*2+0], acc[tt], 0,0,0);
        acc[tt] = __builtin_amdgcn_mfma_f32_16x16x32_bf16(xl0, wx[tt*2+0], acc[tt], 0,0,0);
        acc[tt] = __builtin_amdgcn_mfma_f32_16x16x32_bf16(xh1, wx[tt*2+1], acc[tt], 0,0,0);
        acc[tt] = __builtin_amdgcn_mfma_f32_16x16x32_bf16(xl1, wx[tt*2+1], acc[tt], 0,0,0);
      }
      {
        u32* zs = ringz0 + bt*32768 + ((s&3)<<13);
#pragma unroll
        for (int tt = 0; tt < 4; ++tt) {
          int nc = n0 + (tt<<4) + lrow;
#pragma unroll
          for (int r = 0; r < 4; ++r)
            st32c(zs + ((rb+r)<<9) + nc, __float_as_uint(acc[tt][r] + bz[tt]));
        }
      }
      asm volatile("s_waitcnt vmcnt(0)" ::: "memory");
      __syncthreads();
      if (tid == 0) stf(flD, s + 1);
    }
  }
}

extern "C" void kernel_launch(void* const* d_in, const int* in_sizes, int n_in,
                              void* d_out, int out_size, void* d_ws, size_t ws_size,
                              hipStream_t stream) {
  const float* x     = (const float*)d_in[0];
  const float* w_ih0 = (const float*)d_in[1];
  const float* w_hh0 = (const float*)d_in[2];
  const float* b_ih0 = (const float*)d_in[3];
  const float* b_hh0 = (const float*)d_in[4];
  const float* w_ih1 = (const float*)d_in[5];
  const float* w_hh1 = (const float*)d_in[6];
  const float* b_ih1 = (const float*)d_in[7];
  const float* b_hh1 = (const float*)d_in[8];
  const float* fc1_w = (const float*)d_in[9];
  const float* fc1_b = (const float*)d_in[10];
  const float* fc2_w = (const float*)d_in[11];
  const float* fc2_b = (const float*)d_in[12];
  float* out = (float*)d_out;

  char* ws = (char*)d_ws;
  u32* ring0  = (u32*)(ws);                 // h0: 16bt x 4slots x 16x512 u32 = 2 MB
  u32* ringz0 = (u32*)(ws + (2u<<20));      // z0 f32 bits, 2 MB
  u32* ringz1 = (u32*)(ws + (4u<<20));      // z1 f32 bits, 2 MB
  int* flags  = (int*)(ws + (6u<<20));      // 16bt x 8 x 64B = 8 KB

  init_kernel<<<dim3(4), dim3(512), 0, stream>>>((u32*)(ws + (6u<<20)));
  rnn_kernel<<<dim3(80), dim3(512), 0, stream>>>(
      x, w_ih0, w_hh0, b_ih0, b_hh0, w_ih1, w_hh1, b_ih1, b_hh1,
      fc1_w, fc1_b, fc2_w, fc2_b, out,
      ring0, ringz0, ringz1, flags);
}

// Round 5
// 2013.504 us; speedup vs baseline: 1.0225x; 1.0225x over previous
//
#include <hip/hip_runtime.h>

using bf16x8 = __attribute__((ext_vector_type(8))) short;
using f32x4  = __attribute__((ext_vector_type(4))) float;
typedef unsigned short u16;
typedef unsigned int   u32;
typedef unsigned long long u64;

#define MAX_SPIN 1000000

// B=256,T=256,D=64,H=512,O=10. 80 WGs x 512 thr. role = wg>>4: 0=A(L0 recur),
// 1=C(L1 recur + head), 2=B0, 3=B1 (z1 = W_ih1*h0 + b, n-halves), 4=D (z0 = W_ih0*x + b).
// bt = wg&15. wg = role*16+bt => XCD = bt%8: all 5 roles of a bt share an XCD.
// Recurrences CU-LOCAL: h planes in LDS, W_hh stationary (12 k-slices VGPR/AGPR +
// 4 k-slices LDS). Rings depth 8 (slack ~4-5 stages so flag RTT amortizes).
// Flags: single-writer monotonic stage counters; ONLY tid0 polls (cached), rest
// park on __syncthreads. Certificates: flX = n means stage n-1 done AND its
// prefetch reads of slot (n-1) drained (vmcnt(0) before publish).
// Windows: A needs flD>=s+2 (z0 prefetch), flB*>=s-6 (ring0 slot reuse, depth 8).
//          B needs flA>=t+2 (h0 prefetch), flC>=t-6 (z1 slot reuse).
//          C needs flB*>=t+2 (z1 prefetch). D needs flA>=s-7 (z0 slot reuse).

__device__ __forceinline__ float bf2f(u16 u){ union{u32 i;float f;}v; v.i=((u32)u)<<16; return v.f; }
__device__ __forceinline__ u16 f2bf(float f){ union{float f;u32 i;}v; v.f=f; u32 x=v.i; return (u16)((x+0x7FFFu+((x>>16)&1u))>>16); }
__device__ __forceinline__ bf16x8 load8f(const float* p){
  float4 a=*(const float4*)p; float4 b=*(const float4*)(p+4);
  bf16x8 r; r[0]=(short)f2bf(a.x); r[1]=(short)f2bf(a.y); r[2]=(short)f2bf(a.z); r[3]=(short)f2bf(a.w);
  r[4]=(short)f2bf(b.x); r[5]=(short)f2bf(b.y); r[6]=(short)f2bf(b.z); r[7]=(short)f2bf(b.w); return r;
}
__device__ __forceinline__ int  ldf(int* p){ return __hip_atomic_load(p, __ATOMIC_RELAXED, __HIP_MEMORY_SCOPE_AGENT); }
__device__ __forceinline__ void stf(int* p, int v){ __hip_atomic_store(p, v, __ATOMIC_RELAXED, __HIP_MEMORY_SCOPE_AGENT); }
__device__ __forceinline__ u64  ld64c(const u32* p){ return __hip_atomic_load((const u64*)p, __ATOMIC_RELAXED, __HIP_MEMORY_SCOPE_AGENT); }
__device__ __forceinline__ u32  ld32c(const u32* p){ return __hip_atomic_load(p, __ATOMIC_RELAXED, __HIP_MEMORY_SCOPE_AGENT); }
__device__ __forceinline__ void st32c(u32* p, u32 v){ __hip_atomic_store(p, v, __ATOMIC_RELAXED, __HIP_MEMORY_SCOPE_AGENT); }
__device__ __forceinline__ int waitge(int* p, int tgt){
  int v = ldf(p); int it = 0;
  while (v < tgt && ++it < MAX_SPIN){ __builtin_amdgcn_s_sleep(1); v = ldf(p); }
  return v;
}

__global__ void init_kernel(u32* p){ p[(blockIdx.x<<9) + threadIdx.x] = 0u; }

#define HFRAG(base, ks) (*(const bf16x8*)((base) + (lrow<<10) + ((((ks)<<6)+(lk8<<1)) ^ sw)))

__global__ void __launch_bounds__(512, 2)
rnn_kernel(const float* __restrict__ x,
           const float* __restrict__ w_ih0, const float* __restrict__ w_hh0,
           const float* __restrict__ b_ih0, const float* __restrict__ b_hh0,
           const float* __restrict__ w_ih1, const float* __restrict__ w_hh1,
           const float* __restrict__ b_ih1, const float* __restrict__ b_hh1,
           const float* __restrict__ fc1_w, const float* __restrict__ fc1_b,
           const float* __restrict__ fc2_w, const float* __restrict__ fc2_b,
           float* __restrict__ out,
           u32* __restrict__ ring0, u32* __restrict__ ringz0, u32* __restrict__ ringz1,
           int* __restrict__ flags)
{
  const int tid  = threadIdx.x;
  const int wg   = blockIdx.x;
  const int lane = tid & 63;
  const int ww   = tid >> 6;          // 0..7
  const int role = wg >> 4;           // 0..4
  const int bt   = wg & 15;
  const int b0   = bt << 4;
  const int lrow = lane & 15;
  const int lk8  = (lane >> 4) << 3;
  const int sw   = (lrow & 7) << 4;
  const int rb   = (lane >> 4) << 2;  // D-frag row base

  __shared__ char sm[163840];
  char* smWb  = sm;                    // A/C: 4 k-slices of W_hh, 128 KB
  char* smHhi = sm + 131072;           // h hi plane [16][512] bf16, 16 KB
  char* smHlo = sm + 147456;           // h lo plane, 16 KB

  int* flA  = flags + ((bt<<3) + 0)*16;
  int* flB0 = flags + ((bt<<3) + 1)*16;
  int* flB1 = flags + ((bt<<3) + 2)*16;
  int* flC  = flags + ((bt<<3) + 3)*16;
  int* flD  = flags + ((bt<<3) + 4)*16;

  if (role == 0 || role == 1) {
    // ================= recurrence WG (A: layer0, C: layer1) =================
    const float* Wp = (role == 0) ? w_hh0 : w_hh1;
    const int n0 = ww << 6;            // wave covers cols [n0, n0+64)
    bf16x8 wv[48];                     // k-slices 0..11 x 4 tiles
#pragma unroll
    for (int tt = 0; tt < 4; ++tt) {
      int n = n0 + (tt<<4) + lrow;
#pragma unroll
      for (int ks = 0; ks < 12; ++ks)
        wv[tt*12+ks] = load8f(Wp + n*512 + (ks<<5) + lk8);
    }
#pragma unroll 1
    for (int it = 0; it < 16; ++it) {  // k-slices 12..15 -> LDS
      int cid = (it<<9) + tid;
      int ss = cid >> 11, wc = cid & 2047;
      int n = wc >> 2, k0 = (wc & 3) << 3;
      bf16x8 v = load8f(Wp + n*512 + 384 + (ss<<5) + k0);
      *(bf16x8*)(smWb + (ss<<15) + (n<<6) + ((k0<<1) ^ ((n&3)<<4))) = v;
    }
    __syncthreads();

    const int wl0 = ((lane>>4)<<4) ^ ((lrow&3)<<4);
    int wlb[4];
#pragma unroll
    for (int tt = 0; tt < 4; ++tt) wlb[tt] = ((n0 + (tt<<4) + lrow)<<6) + wl0;

    u32* zring = (role == 0) ? ringz0 : ringz1;
    const u32* zbase = zring + bt*65536;
    int fP = 0, fP2 = 0, fBP0 = 0, fBP1 = 0;   // tid0 cached flag values
    if (tid == 0) {
      if (role == 0) fP = waitge(flD, 1);
      else { fP = waitge(flB0, 1); fP2 = waitge(flB1, 1); }
    }
    __syncthreads();
    float zpf[16];
#pragma unroll
    for (int tt = 0; tt < 4; ++tt) {
      int nc = n0 + (tt<<4) + lrow;
#pragma unroll
      for (int r = 0; r < 4; ++r)
        zpf[tt*4+r] = __uint_as_float(ld32c(zbase + ((rb+r)<<9) + nc));
    }

    for (int s = 0; s < 256; ++s) {
      f32x4 acc[4] = {{0,0,0,0},{0,0,0,0},{0,0,0,0},{0,0,0,0}};
      if (s > 0) {
#pragma unroll
        for (int ks = 0; ks < 16; ++ks) {
          bf16x8 ahi = HFRAG(smHhi, ks);
          bf16x8 alo = HFRAG(smHlo, ks);
          bf16x8 bw0, bw1, bw2, bw3;
          if (ks < 12) { bw0 = wv[ks]; bw1 = wv[12+ks]; bw2 = wv[24+ks]; bw3 = wv[36+ks]; }
          else {
            int sb = (ks-12) << 15;
            bw0 = *(const bf16x8*)(smWb + sb + wlb[0]);
            bw1 = *(const bf16x8*)(smWb + sb + wlb[1]);
            bw2 = *(const bf16x8*)(smWb + sb + wlb[2]);
            bw3 = *(const bf16x8*)(smWb + sb + wlb[3]);
          }
          acc[0] = __builtin_amdgcn_mfma_f32_16x16x32_bf16(ahi, bw0, acc[0], 0,0,0);
          acc[0] = __builtin_amdgcn_mfma_f32_16x16x32_bf16(alo, bw0, acc[0], 0,0,0);
          acc[1] = __builtin_amdgcn_mfma_f32_16x16x32_bf16(ahi, bw1, acc[1], 0,0,0);
          acc[1] = __builtin_amdgcn_mfma_f32_16x16x32_bf16(alo, bw1, acc[1], 0,0,0);
          acc[2] = __builtin_amdgcn_mfma_f32_16x16x32_bf16(ahi, bw2, acc[2], 0,0,0);
          acc[2] = __builtin_amdgcn_mfma_f32_16x16x32_bf16(alo, bw2, acc[2], 0,0,0);
          acc[3] = __builtin_amdgcn_mfma_f32_16x16x32_bf16(ahi, bw3, acc[3], 0,0,0);
          acc[3] = __builtin_amdgcn_mfma_f32_16x16x32_bf16(alo, bw3, acc[3], 0,0,0);
        }
      }
      u32 pk[16];
#pragma unroll
      for (int tt = 0; tt < 4; ++tt)
#pragma unroll
        for (int r = 0; r < 4; ++r) {
          float v = acc[tt][r] + zpf[tt*4+r];
          v = v > 0.f ? v : 0.f;
          u16 hi = f2bf(v); u16 lo = f2bf(v - bf2f(hi));
          pk[tt*4+r] = ((u32)hi << 16) | lo;
        }
      if (role == 0) {                 // ship h0[s]
        u32* rs = ring0 + bt*65536 + ((s&7)<<13);
#pragma unroll
        for (int tt = 0; tt < 4; ++tt) {
          int nc = n0 + (tt<<4) + lrow;
#pragma unroll
          for (int r = 0; r < 4; ++r) st32c(rs + ((rb+r)<<9) + nc, pk[tt*4+r]);
        }
      }
      __syncthreads();                 // h[s-1] plane reads done
#pragma unroll
      for (int tt = 0; tt < 4; ++tt) {
        int cc = n0 + (tt<<4) + lrow;
#pragma unroll
        for (int r = 0; r < 4; ++r) {
          int rr = rb + r;
          int o = (rr<<10) + (((cc<<1)) ^ ((rr&7)<<4));
          *(u16*)(smHhi + o) = (u16)(pk[tt*4+r] >> 16);
          *(u16*)(smHlo + o) = (u16)(pk[tt*4+r] & 0xFFFFu);
        }
      }
      asm volatile("s_waitcnt vmcnt(0)" ::: "memory");  // ring stores + zpf drained
      __syncthreads();
      if (tid == 0) {
        stf((role==0) ? flA : flC, s + 1);
        if (s < 255) {
          if (role == 0) {
            if (fP < s+2) fP = waitge(flD, s+2);
            if (s-6 > 0) {
              if (fBP0 < s-6) fBP0 = waitge(flB0, s-6);
              if (fBP1 < s-6) fBP1 = waitge(flB1, s-6);
            }
          } else {
            if (fP  < s+2) fP  = waitge(flB0, s+2);
            if (fP2 < s+2) fP2 = waitge(flB1, s+2);
          }
        }
      }
      __syncthreads();
      if (s < 255) {                   // prefetch z[s+1]
        const u32* zs = zbase + (((s+1)&7)<<13);
#pragma unroll
        for (int tt = 0; tt < 4; ++tt) {
          int nc = n0 + (tt<<4) + lrow;
#pragma unroll
          for (int r = 0; r < 4; ++r)
            zpf[tt*4+r] = __uint_as_float(ld32c(zs + ((rb+r)<<9) + nc));
        }
      }
    }

    if (role == 1) {                   // ======== head: fc1(relu)+fc2 ========
      float* smF = (float*)sm;
      if (tid < 128) {
        int r = tid >> 3, j = tid & 7;
        const float* wr = fc1_w + (j << 9);
        float accv = fc1_b[j];
        for (int k = 0; k < 512; ++k) {
          int o = (r<<10) + (((k<<1)) ^ ((r&7)<<4));
          float hv = bf2f(*(u16*)(smHhi + o)) + bf2f(*(u16*)(smHlo + o));
          accv += hv * wr[k];
        }
        smF[tid] = accv > 0.f ? accv : 0.f;
      }
      __syncthreads();
      if (tid < 160) {
        int bb = tid / 10, o = tid - bb*10;
        float accv = fc2_b[o];
        const float* w = fc2_w + (o << 3);
#pragma unroll
        for (int j = 0; j < 8; ++j) accv += smF[(bb<<3)+j] * w[j];
        out[(b0 + bb)*10 + o] = accv;
      }
    }
  } else if (role == 2 || role == 3) {
    // ================= B: z1 n-half = W_ih1 * h0[t] + b =================
    const int nb = (role - 2) << 8;
    const int n0 = nb + (ww << 5);
    bf16x8 wv[32];
    float bias[2];
#pragma unroll
    for (int tt = 0; tt < 2; ++tt) {
      int n = n0 + (tt<<4) + lrow;
#pragma unroll
      for (int ks = 0; ks < 16; ++ks)
        wv[tt*16+ks] = load8f(w_ih1 + n*512 + (ks<<5) + lk8);
      bias[tt] = b_ih1[n] + b_hh1[n];
    }
    int* flB = (role == 2) ? flB0 : flB1;
    int fA = 0, fC = 0;
    if (tid == 0) fA = waitge(flA, 1);
    __syncthreads();
    u64 pf[8];
    {
      const u32* rs = ring0 + bt*65536;
#pragma unroll
      for (int k = 0; k < 8; ++k) {
        int q = tid + (k<<9); int r = q >> 8, c = q & 255;
        pf[k] = ld64c(rs + (r<<9) + (c<<1));
      }
    }
    for (int t = 0; t < 256; ++t) {
#pragma unroll
      for (int k = 0; k < 8; ++k) {    // unpack h0[t] -> planes
        int q = tid + (k<<9); int r = q >> 8, c = q & 255;
        u32 e0 = (u32)pf[k], e1 = (u32)(pf[k] >> 32);
        int o = (r<<10) + ((c<<2) ^ ((r&7)<<4));
        *(u32*)(smHhi + o) = (e0 >> 16) | (e1 & 0xFFFF0000u);
        *(u32*)(smHlo + o) = (e0 & 0xFFFFu) | (e1 << 16);
      }
      __syncthreads();
      f32x4 acc[2] = {{0,0,0,0},{0,0,0,0}};
#pragma unroll
      for (int ks = 0; ks < 16; ++ks) {
        bf16x8 ahi = HFRAG(smHhi, ks);
        bf16x8 alo = HFRAG(smHlo, ks);
        acc[0] = __builtin_amdgcn_mfma_f32_16x16x32_bf16(ahi, wv[ks],    acc[0], 0,0,0);
        acc[0] = __builtin_amdgcn_mfma_f32_16x16x32_bf16(alo, wv[ks],    acc[0], 0,0,0);
        acc[1] = __builtin_amdgcn_mfma_f32_16x16x32_bf16(ahi, wv[16+ks], acc[1], 0,0,0);
        acc[1] = __builtin_amdgcn_mfma_f32_16x16x32_bf16(alo, wv[16+ks], acc[1], 0,0,0);
      }
      {
        u32* zs = ringz1 + bt*65536 + ((t&7)<<13);
#pragma unroll
        for (int tt = 0; tt < 2; ++tt) {
          int nc = n0 + (tt<<4) + lrow;
#pragma unroll
          for (int r = 0; r < 4; ++r)
            st32c(zs + ((rb+r)<<9) + nc, __float_as_uint(acc[tt][r] + bias[tt]));
        }
      }
      asm volatile("s_waitcnt vmcnt(0)" ::: "memory");  // z stores + pf loads drained
      __syncthreads();                 // also: plane reads done before next unpack
      if (tid == 0) {
        stf(flB, t + 1);
        if (t < 255) {
          if (fA < t+2) fA = waitge(flA, t+2);
          if (t-6 > 0 && fC < t-6) fC = waitge(flC, t-6);
        }
      }
      __syncthreads();
      if (t < 255) {
        const u32* rs = ring0 + bt*65536 + (((t+1)&7)<<13);
#pragma unroll
        for (int k = 0; k < 8; ++k) {
          int q = tid + (k<<9); int r = q >> 8, c = q & 255;
          pf[k] = ld64c(rs + (r<<9) + (c<<1));
        }
      }
    }
  } else {
    // ================= D: z0 = W_ih0 * x_s + b (runs ahead) =================
    const int n0 = ww << 6;
    bf16x8 wx[8];
    float bz[4];
#pragma unroll
    for (int tt = 0; tt < 4; ++tt) {
      int n = n0 + (tt<<4) + lrow;
      wx[tt*2+0] = load8f(w_ih0 + n*64 + lk8);
      wx[tt*2+1] = load8f(w_ih0 + n*64 + 32 + lk8);
      bz[tt] = b_ih0[n] + b_hh0[n];
    }
    int fA = 0;
    for (int s = 0; s < 256; ++s) {
      bf16x8 xh0, xl0, xh1, xl1;
      const float* xp = x + ((size_t)(b0 + lrow)*256 + s)*64 + lk8;
#pragma unroll
      for (int j = 0; j < 8; ++j) {
        float f0 = xp[j], f1 = xp[32+j];
        u16 h0 = f2bf(f0); xh0[j] = (short)h0; xl0[j] = (short)f2bf(f0 - bf2f(h0));
        u16 h1 = f2bf(f1); xh1[j] = (short)h1; xl1[j] = (short)f2bf(f1 - bf2f(h1));
      }
      f32x4 acc[4] = {{0,0,0,0},{0,0,0,0},{0,0,0,0},{0,0,0,0}};
#pragma unroll
      for (int tt = 0; tt < 4; ++tt) {
        acc[tt] = __builtin_amdgcn_mfma_f32_16x16x32_bf16(xh0, wx[tt*2+0], acc[tt], 0,0,0);
        acc[tt] = __builtin_amdgcn_mfma_f32_16x16x32_bf16(xl0, wx[tt*2+0], acc[tt], 0,0,0);
        acc[tt] = __builtin_amdgcn_mfma_f32_16x16x32_bf16(xh1, wx[tt*2+1], acc[tt], 0,0,0);
        acc[tt] = __builtin_amdgcn_mfma_f32_16x16x32_bf16(xl1, wx[tt*2+1], acc[tt], 0,0,0);
      }
      if (s >= 8) {                    // z0 slot reuse gate (depth 8)
        if (tid == 0 && fA < s-7) fA = waitge(flA, s-7);
        __syncthreads();
      }
      {
        u32* zs = ringz0 + bt*65536 + ((s&7)<<13);
#pragma unroll
        for (int tt = 0; tt < 4; ++tt) {
          int nc = n0 + (tt<<4) + lrow;
#pragma unroll
          for (int r = 0; r < 4; ++r)
            st32c(zs + ((rb+r)<<9) + nc, __float_as_uint(acc[tt][r] + bz[tt]));
        }
      }
      asm volatile("s_waitcnt vmcnt(0)" ::: "memory");
      __syncthreads();
      if (tid == 0) stf(flD, s + 1);
    }
  }
}

extern "C" void kernel_launch(void* const* d_in, const int* in_sizes, int n_in,
                              void* d_out, int out_size, void* d_ws, size_t ws_size,
                              hipStream_t stream) {
  const float* x     = (const float*)d_in[0];
  const float* w_ih0 = (const float*)d_in[1];
  const float* w_hh0 = (const float*)d_in[2];
  const float* b_ih0 = (const float*)d_in[3];
  const float* b_hh0 = (const float*)d_in[4];
  const float* w_ih1 = (const float*)d_in[5];
  const float* w_hh1 = (const float*)d_in[6];
  const float* b_ih1 = (const float*)d_in[7];
  const float* b_hh1 = (const float*)d_in[8];
  const float* fc1_w = (const float*)d_in[9];
  const float* fc1_b = (const float*)d_in[10];
  const float* fc2_w = (const float*)d_in[11];
  const float* fc2_b = (const float*)d_in[12];
  float* out = (float*)d_out;

  char* ws = (char*)d_ws;
  u32* ring0  = (u32*)(ws);                  // h0: 16bt x 8slots x 16x512 u32 = 4 MB
  u32* ringz0 = (u32*)(ws + (4u<<20));       // z0 f32 bits, 4 MB
  u32* ringz1 = (u32*)(ws + (8u<<20));       // z1 f32 bits, 4 MB
  int* flags  = (int*)(ws + (12u<<20));      // 16bt x 8 x 64B = 8 KB

  init_kernel<<<dim3(4), dim3(512), 0, stream>>>((u32*)(ws + (12u<<20)));
  rnn_kernel<<<dim3(80), dim3(512), 0, stream>>>(
      x, w_ih0, w_hh0, b_ih0, b_hh0, w_ih1, w_hh1, b_ih1, b_hh1,
      fc1_w, fc1_b, fc2_w, fc2_b, out,
      ring0, ringz0, ringz1, flags);
}